// Round 18
// baseline (103.125 us; speedup 1.0000x reference)
//
#include <hip/hip_runtime.h>
#include <hip/hip_fp8.h>
#include <stdint.h>

#define N2 2048
#define NN (2048UL * 2048UL)

typedef __attribute__((ext_vector_type(4))) float f32x4;
typedef __attribute__((ext_vector_type(4))) int   i32x4;
typedef __attribute__((ext_vector_type(8))) int   i32x8;

__device__ __forceinline__ unsigned char f2f8(float x) {
    __hip_fp8_e4m3 t(x);          // OCP e4m3fn
    return t.__x;
}
__device__ __forceinline__ float f82f(unsigned char b) {
    __hip_fp8_e4m3 t;
    t.__x = b;
    return (float)t;
}

// 4x f32 -> packed fp8 dword (HW cvt when available)
__device__ __forceinline__ unsigned f2f8x4(const float* a) {
#if __has_builtin(__builtin_amdgcn_cvt_pk_fp8_f32)
    int w = 0;
    w = __builtin_amdgcn_cvt_pk_fp8_f32(a[0], a[1], w, false);
    w = __builtin_amdgcn_cvt_pk_fp8_f32(a[2], a[3], w, true);
    return (unsigned)w;
#else
    union { unsigned char b[4]; unsigned v; } o;
    #pragma unroll
    for (int i = 0; i < 4; i++) o.b[i] = f2f8(a[i]);
    return o.v;
#endif
}
__device__ __forceinline__ uint2 f2f8x8(const float* a) {
    uint2 r; r.x = f2f8x4(a); r.y = f2f8x4(a + 4);
    return r;
}

__device__ __forceinline__ void gload16(const void* g, void* l) {
    __builtin_amdgcn_global_load_lds(
        (const __attribute__((address_space(1))) unsigned int*)g,
        (__attribute__((address_space(3))) unsigned int*)l, 16, 0, 0);
}

// ---------------------------------------------------------------------------
// combine v6 (r17 champion, verbatim): half-width threads, full occupancy.
// ---------------------------------------------------------------------------
__global__ __launch_bounds__(512, 8) void combine_kernel(
    const float* __restrict__ A, const float* __restrict__ w01,
    const float* __restrict__ w02, const float* __restrict__ w11,
    unsigned char* __restrict__ HA, unsigned char* __restrict__ HBt,
    unsigned char* __restrict__ HB2t, float* __restrict__ PB2) {
    __shared__ float s[3][2][5];
    __shared__ float tile[2][64][33];   // 16.9 KB
    const int tid = threadIdx.x;
    if (tid < 6) {
        const int wi = tid >> 1, c = tid & 1;
        const float* w = (wi == 0 ? w01 : (wi == 1 ? w02 : w11)) + c * 5;
        float mx = w[0];
        for (int e = 1; e < 5; e++) mx = fmaxf(mx, w[e]);
        float ex[5], sum = 0.f;
        for (int e = 0; e < 5; e++) { ex[e] = expf(w[e] - mx); sum += ex[e]; }
        for (int e = 0; e < 5; e++) s[wi][c][e] = ex[e] / sum;
    }
    __syncthreads();

    const int nr  = tid >> 4;          // 0..31 (n within tile)
    const int mc4 = (tid & 15) * 4;    // 0..60 (m offset)
    const size_t gn = (size_t)blockIdx.y * 32 + nr;
    const size_t gm = (size_t)blockIdx.x * 64 + mc4;
    const float* ap = A + gn * N2 + gm;

    float4 av[5];
    #pragma unroll
    for (int e = 0; e < 5; e++) av[e] = *(const float4*)(ap + (size_t)e * NN);

    float acc[6][4] = {};
    #pragma unroll
    for (int e = 0; e < 5; e++) {
        const float a[4] = {av[e].x, av[e].y, av[e].z, av[e].w};
        #pragma unroll
        for (int c = 0; c < 2; c++) {
            const float q0 = s[0][c][e], q1 = s[1][c][e], q2 = s[2][c][e];
            #pragma unroll
            for (int i = 0; i < 4; i++) {
                acc[c][i]     += q0 * a[i];
                acc[2 + c][i] += q1 * a[i];
                acc[4 + c][i] += q2 * a[i];
            }
        }
    }

    #pragma unroll
    for (int c = 0; c < 2; c++)
        *(unsigned*)&HA[(size_t)c * NN + gn * N2 + gm] = f2f8x4(acc[c]);

    #pragma unroll
    for (int c = 0; c < 2; c++) {
        float v = acc[4 + c][0] + acc[4 + c][1] + acc[4 + c][2] + acc[4 + c][3];
        v += __shfl_xor(v, 1);
        v += __shfl_xor(v, 2);
        v += __shfl_xor(v, 4);
        v += __shfl_xor(v, 8);
        if ((tid & 15) == 0)
            PB2[(size_t)c * 32 * 2048 + (size_t)blockIdx.x * 2048 + gn] = v;
    }

    #pragma unroll
    for (int rr = 0; rr < 2; rr++) {
        __syncthreads();
        #pragma unroll
        for (int rl = 0; rl < 2; rl++)
            #pragma unroll
            for (int i = 0; i < 4; i++)
                tile[rl][mc4 + i][nr] = acc[2 + rr * 2 + rl][i];
        __syncthreads();
        {
            const int ch   = tid >> 8;          // 0..1
            const int mrow = (tid >> 2) & 63;   // 0..63
            const int ns   = (tid & 3) * 8;     // 0,8,16,24
            float a[8];
            const float4 t0 = *(const float4*)&tile[ch][mrow][ns];
            const float4 t1 = *(const float4*)&tile[ch][mrow][ns + 4];
            a[0] = t0.x; a[1] = t0.y; a[2] = t0.z; a[3] = t0.w;
            a[4] = t1.x; a[5] = t1.y; a[6] = t1.z; a[7] = t1.w;
            unsigned char* dst = (rr == 0 ? HBt : HB2t) + (size_t)ch * NN
                + ((size_t)blockIdx.x * 64 + mrow) * N2
                + (size_t)blockIdx.y * 32 + ns;
            *(uint2*)dst = f2f8x8(a);
        }
    }
}

// ---------------------------------------------------------------------------
// b2sum[c][n] = sum_bx PB2[c][bx][n]
// ---------------------------------------------------------------------------
__global__ __launch_bounds__(256) void b2fold_kernel(
    const float* __restrict__ PB2, float* __restrict__ b2sum) {
    const int r = blockIdx.x * 256 + threadIdx.x;   // c*2048 + n
    const int c = r >> 11, n = r & 2047;
    float sum = 0.f;
    #pragma unroll
    for (int bx = 0; bx < 32; bx++) sum += PB2[c * 65536 + bx * 2048 + n];
    b2sum[r] = sum;
}

// ---------------------------------------------------------------------------
// MX-fp8 GEMM, B^T input: C[c] = A[c] @ B[c].
// r18 change (single lever): REMOVED the intra-tile lgkmcnt(4)/(0) +
// sched_barrier pins around the MFMA groups. The compiler now interleaves
// the 16 ds_reads with the 16 MFMAs via its own counted lgkmcnt (m141
// lesson: order-pinning defeats compiler scheduling; LDS and MFMA pipes
// are independent -> overlap was being serialized).
// Correctness skeleton unchanged: vmcnt(6/0) -> s_barrier -> sched_barrier
// per tile; 3 buffers, 2-ahead staging; reads are typed loads consumed by
// MFMAs within the iteration (data-deps force completion before the next
// barrier, so the r12 staging-overwrite argument holds verbatim).
// ---------------------------------------------------------------------------
#define GBM 256
#define GBN 128
#define GBK 128
#define BUF_BYTES 49152   // A 32KB + B 16KB
#define B_OFF 32768
#define SCALE1 0x7F7F7F7F  // e8m0 1.0 in every byte

template <int MODE>
__global__ __launch_bounds__(512, 2) void gemm_mx(
    const unsigned char* __restrict__ A, const unsigned char* __restrict__ Bt,
    void* __restrict__ Cout, float* __restrict__ P,
    const float* __restrict__ sfac) {
    __shared__ unsigned char lds[3 * BUF_BYTES];   // 144 KB

    const int tid  = threadIdx.x;
    const int wave = tid >> 6, lane = tid & 63;
    const int wm = wave >> 1, wn = wave & 1;
    const int wr = wm * 64;             // 0,64,128,192
    const int wc = wn * 64;             // 0,64
    const int l16 = lane & 15, lhi = lane >> 4;

    const int brow = blockIdx.y * GBM;
    const int bcol = blockIdx.x * GBN;
    const size_t cz = (size_t)blockIdx.z * NN;
    const unsigned char* Ab  = A  + cz + (size_t)brow * N2;
    const unsigned char* Btb = Bt + cz + (size_t)bcol * N2;

    const unsigned char* src[6];
    #pragma unroll
    for (int L = 0; L < 4; L++) {
        const int g = L * 512 + tid;
        const int r = g >> 3, s = (g & 7) ^ (r & 7);
        src[L] = Ab + (size_t)r * N2 + s * 16;
    }
    #pragma unroll
    for (int L = 4; L < 6; L++) {
        const int h = (L - 4) * 512 + tid;
        const int r = h >> 3, s = (h & 7) ^ (r & 7);
        src[L] = Btb + (size_t)r * N2 + s * 16;
    }

    #define STAGE6(buf, k0)                                                   \
        do {                                                                  \
            unsigned char* dst = lds + (buf) * BUF_BYTES + tid * 16;          \
            _Pragma("unroll")                                                 \
            for (int i = 0; i < 6; i++)                                       \
                gload16(src[i] + (k0), dst + i * 8192);                       \
        } while (0)

    f32x4 acc[4][4] = {};

    STAGE6(0, 0);
    STAGE6(1, GBK);

    const int nt = N2 / GBK;   // 16
    for (int t = 0; t < nt; ++t) {
        const unsigned char* base = lds + (t % 3) * BUF_BYTES;

        if (t < nt - 1) asm volatile("s_waitcnt vmcnt(6)" ::: "memory");
        else            asm volatile("s_waitcnt vmcnt(0)" ::: "memory");
        __builtin_amdgcn_s_barrier();          // tile t fully staged, all waves
        __builtin_amdgcn_sched_barrier(0);

        i32x8 af0[2], bfr[4], af1[2];
        #pragma unroll
        for (int m = 0; m < 2; m++) {
            const int row = wr + m * 16 + l16;
            const unsigned char* rp = base + row * 128;
            const i32x4 lo = *(const i32x4*)(rp + (((2 * lhi)     ^ (row & 7)) * 16));
            const i32x4 hi = *(const i32x4*)(rp + (((2 * lhi + 1) ^ (row & 7)) * 16));
            #pragma unroll
            for (int q = 0; q < 4; q++) { af0[m][q] = lo[q]; af0[m][4 + q] = hi[q]; }
        }
        #pragma unroll
        for (int n = 0; n < 4; n++) {
            const int row = wc + n * 16 + l16;
            const unsigned char* rp = base + B_OFF + row * 128;
            const i32x4 lo = *(const i32x4*)(rp + (((2 * lhi)     ^ (row & 7)) * 16));
            const i32x4 hi = *(const i32x4*)(rp + (((2 * lhi + 1) ^ (row & 7)) * 16));
            #pragma unroll
            for (int q = 0; q < 4; q++) { bfr[n][q] = lo[q]; bfr[n][4 + q] = hi[q]; }
        }
        #pragma unroll
        for (int m = 0; m < 2; m++) {
            const int row = wr + 32 + m * 16 + l16;
            const unsigned char* rp = base + row * 128;
            const i32x4 lo = *(const i32x4*)(rp + (((2 * lhi)     ^ (row & 7)) * 16));
            const i32x4 hi = *(const i32x4*)(rp + (((2 * lhi + 1) ^ (row & 7)) * 16));
            #pragma unroll
            for (int q = 0; q < 4; q++) { af1[m][q] = lo[q]; af1[m][4 + q] = hi[q]; }
        }
        if (t + 2 < nt) STAGE6((t + 2) % 3, (t + 2) * GBK);

        // no lgkmcnt/sched_barrier pins: compiler interleaves reads & MFMAs
        __builtin_amdgcn_s_setprio(1);
        #pragma unroll
        for (int m = 0; m < 2; m++)
            #pragma unroll
            for (int n = 0; n < 4; n++)
                acc[m][n] = __builtin_amdgcn_mfma_scale_f32_16x16x128_f8f6f4(
                    af0[m], bfr[n], acc[m][n], 0, 0, 0, SCALE1, 0, SCALE1);
        #pragma unroll
        for (int m = 0; m < 2; m++)
            #pragma unroll
            for (int n = 0; n < 4; n++)
                acc[2 + m][n] = __builtin_amdgcn_mfma_scale_f32_16x16x128_f8f6f4(
                    af1[m], bfr[n], acc[2 + m][n], 0, 0, 0, SCALE1, 0, SCALE1);
        __builtin_amdgcn_s_setprio(0);
    }
    #undef STAGE6

    if constexpr (MODE == 0) {
        unsigned char* Cb = (unsigned char*)Cout + cz + (size_t)brow * N2 + bcol;
        #pragma unroll
        for (int m = 0; m < 4; m++) {
            const int r0 = wr + m * 16 + lhi * 4;
            #pragma unroll
            for (int n = 0; n < 4; n++) {
                const int c0 = wc + n * 16 + l16;
                #pragma unroll
                for (int j = 0; j < 4; j++)
                    Cb[(size_t)(r0 + j) * N2 + c0] = f2f8(acc[m][n][j]);
            }
        }
        const size_t pb = (size_t)(blockIdx.x * 2 + wn) * 4096
                        + (size_t)blockIdx.z * 2048 + brow + wr;
        #pragma unroll
        for (int m = 0; m < 4; m++)
            #pragma unroll
            for (int j = 0; j < 4; j++) {
                float ps = acc[m][0][j] + acc[m][1][j] + acc[m][2][j] + acc[m][3][j];
                ps += __shfl_xor(ps, 1);
                ps += __shfl_xor(ps, 2);
                ps += __shfl_xor(ps, 4);
                ps += __shfl_xor(ps, 8);
                if (l16 == 0) P[pb + m * 16 + lhi * 4 + j] = ps;
            }
    } else {
        float* Cb = (float*)Cout + cz + (size_t)brow * N2 + bcol;
        float sf[4][4];
        #pragma unroll
        for (int m = 0; m < 4; m++)
            #pragma unroll
            for (int j = 0; j < 4; j++)
                sf[m][j] = sfac[blockIdx.z * 2048 + brow + wr + m * 16 + lhi * 4 + j];
        #pragma unroll
        for (int m = 0; m < 4; m++) {
            const int r0 = wr + m * 16 + lhi * 4;
            #pragma unroll
            for (int n = 0; n < 4; n++) {
                const int c0 = wc + n * 16 + l16;
                #pragma unroll
                for (int j = 0; j < 4; j++)
                    Cb[(size_t)(r0 + j) * N2 + c0] = acc[m][n][j] * sf[m][j];
            }
        }
    }
}

// ---------------------------------------------------------------------------
// merged gemv+dinv (unchanged)
// ---------------------------------------------------------------------------
__device__ __forceinline__ float block_sum256(float v) {
    #pragma unroll
    for (int off = 32; off; off >>= 1) v += __shfl_xor(v, off, 64);
    __shared__ float wsum[4];
    if ((threadIdx.x & 63) == 0) wsum[threadIdx.x >> 6] = v;
    __syncthreads();
    return wsum[0] + wsum[1] + wsum[2] + wsum[3];
}

__global__ __launch_bounds__(256) void gemv_sfac_kernel(
    const unsigned char* __restrict__ C0, const float* __restrict__ b2sum,
    const float* __restrict__ P, float* __restrict__ sfac) {
    const size_t r = blockIdx.x;               // 0..4095 (c*2048 + row)
    const int tid = threadIdx.x;

    float s0 = 0.f;
    if (tid < 64) {
        float v = P[(size_t)(tid & 31) * 4096 + r];
        v += __shfl_xor(v, 1);
        v += __shfl_xor(v, 2);
        v += __shfl_xor(v, 4);
        v += __shfl_xor(v, 8);
        v += __shfl_xor(v, 16);
        s0 = v;
    }

    const unsigned char* row = C0 + r * N2;
    const float* bs = b2sum + ((r >> 11) << 11);
    const int base = tid * 8;
    union { uint2 v; unsigned char b[8]; } u;
    u.v = *(const uint2*)&row[base];
    float sum = 0.f;
    #pragma unroll
    for (int i = 0; i < 8; i++) sum += f82f(u.b[i]) * bs[base + i];
    const float tot = block_sum256(sum);
    if (tid == 0) {
        const float d0 = s0 > 0.f ? rsqrtf(s0) : 0.f;
        const float deg1 = d0 * tot;
        sfac[r] = d0 * (deg1 > 0.f ? rsqrtf(deg1) : 0.f);
    }
}

// ---------------------------------------------------------------------------
// head: 64 blocks x 8 targets; block 0 also emits all_Ws. Unchanged.
// ---------------------------------------------------------------------------
__global__ __launch_bounds__(256) void head_kernel(
    const float* __restrict__ X, const float* __restrict__ gcn_w,
    const float* __restrict__ gcn_b, const float* __restrict__ lin_w,
    const float* __restrict__ lin_b, const int* __restrict__ tx,
    const float* __restrict__ w01, const float* __restrict__ w02,
    const float* __restrict__ w11,
    float* __restrict__ y, float* __restrict__ allw) {
    __shared__ float xr[8][512];    // 16 KB
    __shared__ float xk[8][132];    // padded
    __shared__ int trg[8];
    const int tid = threadIdx.x, b = blockIdx.x;
    if (tid < 8) trg[tid] = tx[b * 8 + tid];
    __syncthreads();
    #pragma unroll
    for (int q = 0; q < 4; q++) {
        const int idx = q * 1024 + tid * 4;
        const int t = idx >> 9, col = idx & 511;
        *(float4*)&xr[t][col] = *(const float4*)&X[(size_t)trg[t] * 512 + col];
    }
    __syncthreads();
    const int k = tid & 127, tp = tid >> 7;
    const float* wrp = gcn_w + (size_t)k * 512;
    float d[4] = {0.f, 0.f, 0.f, 0.f};
    for (int i = 0; i < 512; i += 4) {
        const float4 wv = *(const float4*)&wrp[i];
        #pragma unroll
        for (int tt = 0; tt < 4; tt++) {
            const float* xp = xr[tp * 4 + tt];
            d[tt] += xp[i] * wv.x + xp[i+1] * wv.y + xp[i+2] * wv.z + xp[i+3] * wv.w;
        }
    }
    const float gb = gcn_b[k];
    #pragma unroll
    for (int tt = 0; tt < 4; tt++) xk[tp * 4 + tt][k] = fmaxf(d[tt] + gb, 0.f);
    __syncthreads();
    if (tid < 64) {
        const int t = tid >> 3, o = tid & 7;
        float a = lin_b[o];
        const float* lw = lin_w + o * 256;
        for (int kk = 0; kk < 128; kk++)
            a += xk[t][kk] * (lw[kk] + lw[128 + kk]);
        y[(size_t)(b * 8 + t) * 8 + o] = a;
    }
    if (b == 0 && tid >= 64 && tid < 70) {
        const int t6 = tid - 64;
        const int wi = t6 >> 1, c = t6 & 1;
        const float* w = (wi == 0 ? w01 : (wi == 1 ? w02 : w11)) + c * 5;
        float mx = w[0];
        for (int e = 1; e < 5; e++) mx = fmaxf(mx, w[e]);
        float ex[5], sum = 0.f;
        for (int e = 0; e < 5; e++) { ex[e] = expf(w[e] - mx); sum += ex[e]; }
        for (int e = 0; e < 5; e++) allw[t6 * 5 + e] = ex[e] / sum;
    }
}

// ---------------------------------------------------------------------------
extern "C" void kernel_launch(void* const* d_in, const int* in_sizes, int n_in,
                              void* d_out, int out_size, void* d_ws, size_t ws_size,
                              hipStream_t stream) {
    const float* A     = (const float*)d_in[0];
    const float* X     = (const float*)d_in[1];
    const float* w01   = (const float*)d_in[2];
    const float* w02   = (const float*)d_in[3];
    const float* w11   = (const float*)d_in[4];
    const float* gcn_w = (const float*)d_in[5];
    const float* gcn_b = (const float*)d_in[6];
    const float* lin_w = (const float*)d_in[7];
    const float* lin_b = (const float*)d_in[8];
    const int*   tx    = (const int*)d_in[9];

    float* out  = (float*)d_out;
    float* y    = out;                 // [512, 8]
    float* allw = out + 4096;          // [3, 2, 5]
    float* H    = out + 4126;          // [2, 2048, 2048] fp32 final output

    unsigned char* HA   = (unsigned char*)d_ws;         // [2,N,N] fp8
    unsigned char* HBt  = HA + 2 * NN;                  // [2,N,N] fp8 (B^T)
    unsigned char* HB2t = HBt + 2 * NN;                 // [2,N,N] fp8 (B^T)
    unsigned char* C0   = HB2t + 2 * NN;                // [2,N,N] fp8 layer-0 product
    float* P     = (float*)(C0 + 2 * NN);               // [32][4096] partials (f32)
    float* PB2   = P + 32 * 4096;                       // [2][32][2048]
    float* b2sum = PB2 + 2 * 32 * 2048;                 // [4096]
    float* sfac  = b2sum + 4096;                        // [4096]

    combine_kernel<<<dim3(32, 64), 512, 0, stream>>>(A, w01, w02, w11,
                                                     HA, HBt, HB2t, PB2);
    b2fold_kernel<<<16, 256, 0, stream>>>(PB2, b2sum);
    gemm_mx<0><<<dim3(16, 8, 2), 512, 0, stream>>>(HA, HBt, C0, P, nullptr);
    gemv_sfac_kernel<<<4096, 256, 0, stream>>>(C0, b2sum, P, sfac);
    gemm_mx<1><<<dim3(16, 8, 2), 512, 0, stream>>>(C0, HB2t, H, nullptr, sfac);
    head_kernel<<<64, 256, 0, stream>>>(X, gcn_w, gcn_b, lin_w, lin_b, tx,
                                        w01, w02, w11, y, allw);
}

// Round 19
// 100.513 us; speedup vs baseline: 1.0260x; 1.0260x over previous
//
#include <hip/hip_runtime.h>
#include <hip/hip_fp8.h>
#include <stdint.h>

#define N2 2048
#define NN (2048UL * 2048UL)

typedef __attribute__((ext_vector_type(4))) float f32x4;
typedef __attribute__((ext_vector_type(4))) int   i32x4;
typedef __attribute__((ext_vector_type(8))) int   i32x8;

__device__ __forceinline__ unsigned char f2f8(float x) {
    __hip_fp8_e4m3 t(x);          // OCP e4m3fn
    return t.__x;
}
__device__ __forceinline__ float f82f(unsigned char b) {
    __hip_fp8_e4m3 t;
    t.__x = b;
    return (float)t;
}

// 4x f32 -> packed fp8 dword (HW cvt when available)
__device__ __forceinline__ unsigned f2f8x4(const float* a) {
#if __has_builtin(__builtin_amdgcn_cvt_pk_fp8_f32)
    int w = 0;
    w = __builtin_amdgcn_cvt_pk_fp8_f32(a[0], a[1], w, false);
    w = __builtin_amdgcn_cvt_pk_fp8_f32(a[2], a[3], w, true);
    return (unsigned)w;
#else
    union { unsigned char b[4]; unsigned v; } o;
    #pragma unroll
    for (int i = 0; i < 4; i++) o.b[i] = f2f8(a[i]);
    return o.v;
#endif
}
__device__ __forceinline__ uint2 f2f8x8(const float* a) {
    uint2 r; r.x = f2f8x4(a); r.y = f2f8x4(a + 4);
    return r;
}

__device__ __forceinline__ void gload16(const void* g, void* l) {
    __builtin_amdgcn_global_load_lds(
        (const __attribute__((address_space(1))) unsigned int*)g,
        (__attribute__((address_space(3))) unsigned int*)l, 16, 0, 0);
}

// ---------------------------------------------------------------------------
// combine v6 (r17 champion, verbatim): half-width threads, full occupancy.
// ---------------------------------------------------------------------------
__global__ __launch_bounds__(512, 8) void combine_kernel(
    const float* __restrict__ A, const float* __restrict__ w01,
    const float* __restrict__ w02, const float* __restrict__ w11,
    unsigned char* __restrict__ HA, unsigned char* __restrict__ HBt,
    unsigned char* __restrict__ HB2t, float* __restrict__ PB2) {
    __shared__ float s[3][2][5];
    __shared__ float tile[2][64][33];   // 16.9 KB
    const int tid = threadIdx.x;
    if (tid < 6) {
        const int wi = tid >> 1, c = tid & 1;
        const float* w = (wi == 0 ? w01 : (wi == 1 ? w02 : w11)) + c * 5;
        float mx = w[0];
        for (int e = 1; e < 5; e++) mx = fmaxf(mx, w[e]);
        float ex[5], sum = 0.f;
        for (int e = 0; e < 5; e++) { ex[e] = expf(w[e] - mx); sum += ex[e]; }
        for (int e = 0; e < 5; e++) s[wi][c][e] = ex[e] / sum;
    }
    __syncthreads();

    const int nr  = tid >> 4;          // 0..31 (n within tile)
    const int mc4 = (tid & 15) * 4;    // 0..60 (m offset)
    const size_t gn = (size_t)blockIdx.y * 32 + nr;
    const size_t gm = (size_t)blockIdx.x * 64 + mc4;
    const float* ap = A + gn * N2 + gm;

    float4 av[5];
    #pragma unroll
    for (int e = 0; e < 5; e++) av[e] = *(const float4*)(ap + (size_t)e * NN);

    float acc[6][4] = {};
    #pragma unroll
    for (int e = 0; e < 5; e++) {
        const float a[4] = {av[e].x, av[e].y, av[e].z, av[e].w};
        #pragma unroll
        for (int c = 0; c < 2; c++) {
            const float q0 = s[0][c][e], q1 = s[1][c][e], q2 = s[2][c][e];
            #pragma unroll
            for (int i = 0; i < 4; i++) {
                acc[c][i]     += q0 * a[i];
                acc[2 + c][i] += q1 * a[i];
                acc[4 + c][i] += q2 * a[i];
            }
        }
    }

    #pragma unroll
    for (int c = 0; c < 2; c++)
        *(unsigned*)&HA[(size_t)c * NN + gn * N2 + gm] = f2f8x4(acc[c]);

    #pragma unroll
    for (int c = 0; c < 2; c++) {
        float v = acc[4 + c][0] + acc[4 + c][1] + acc[4 + c][2] + acc[4 + c][3];
        v += __shfl_xor(v, 1);
        v += __shfl_xor(v, 2);
        v += __shfl_xor(v, 4);
        v += __shfl_xor(v, 8);
        if ((tid & 15) == 0)
            PB2[(size_t)c * 32 * 2048 + (size_t)blockIdx.x * 2048 + gn] = v;
    }

    #pragma unroll
    for (int rr = 0; rr < 2; rr++) {
        __syncthreads();
        #pragma unroll
        for (int rl = 0; rl < 2; rl++)
            #pragma unroll
            for (int i = 0; i < 4; i++)
                tile[rl][mc4 + i][nr] = acc[2 + rr * 2 + rl][i];
        __syncthreads();
        {
            const int ch   = tid >> 8;          // 0..1
            const int mrow = (tid >> 2) & 63;   // 0..63
            const int ns   = (tid & 3) * 8;     // 0,8,16,24
            float a[8];
            const float4 t0 = *(const float4*)&tile[ch][mrow][ns];
            const float4 t1 = *(const float4*)&tile[ch][mrow][ns + 4];
            a[0] = t0.x; a[1] = t0.y; a[2] = t0.z; a[3] = t0.w;
            a[4] = t1.x; a[5] = t1.y; a[6] = t1.z; a[7] = t1.w;
            unsigned char* dst = (rr == 0 ? HBt : HB2t) + (size_t)ch * NN
                + ((size_t)blockIdx.x * 64 + mrow) * N2
                + (size_t)blockIdx.y * 32 + ns;
            *(uint2*)dst = f2f8x8(a);
        }
    }
}

// ---------------------------------------------------------------------------
// b2sum[c][n] = sum_bx PB2[c][bx][n]
// ---------------------------------------------------------------------------
__global__ __launch_bounds__(256) void b2fold_kernel(
    const float* __restrict__ PB2, float* __restrict__ b2sum) {
    const int r = blockIdx.x * 256 + threadIdx.x;   // c*2048 + n
    const int c = r >> 11, n = r & 2047;
    float sum = 0.f;
    #pragma unroll
    for (int bx = 0; bx < 32; bx++) sum += PB2[c * 65536 + bx * 2048 + n];
    b2sum[r] = sum;
}

// ---------------------------------------------------------------------------
// MX-fp8 GEMM v2: 128x128 tile, BK=128, 256 threads (4 waves, 2Mx2N),
// per-wave 64x64 = 4x4 frags of mfma_scale_f32_16x16x128_f8f6f4 (scales=1).
// DOUBLE-buffered LDS (2 x 32KB = 64KB) -> 2 blocks/CU (grid 512 = 2/CU):
// cross-block overlap fills the barrier-drain stalls that the old 1-block/CU
// 256x128 geometry could not hide (r14/r18 intra-block tweaks were null).
// Per tile: vmcnt(8) [own tile-t loads] -> s_barrier [join] -> 16 ds_read
// + 16 MFMA -> sched_barrier|s_barrier|sched_barrier -> stage t+2 into
// buf[t%2] (readers provably retired: reads feed MFMAs issued before the
// pinned barrier). Swizzle: slot ^= (row&7) on source and read (2-way only).
// MODE 0: fp8 C store + per-block partial row sums P.
// MODE 1: fp32 C store scaled by sfac[row] (final H).
// ---------------------------------------------------------------------------
#define GBM 128
#define GBN 128
#define GBK 128
#define BUF_BYTES 32768   // A 16KB + B 16KB
#define B_OFF 16384
#define SCALE1 0x7F7F7F7F  // e8m0 1.0 in every byte

template <int MODE>
__global__ __launch_bounds__(256, 2) void gemm_mx(
    const unsigned char* __restrict__ A, const unsigned char* __restrict__ Bt,
    void* __restrict__ Cout, float* __restrict__ P,
    const float* __restrict__ sfac) {
    __shared__ unsigned char lds[2 * BUF_BYTES];   // 64 KB

    const int tid  = threadIdx.x;
    const int wave = tid >> 6, lane = tid & 63;
    const int wm = wave >> 1, wn = wave & 1;
    const int wr = wm * 64;             // 0,64
    const int wc = wn * 64;             // 0,64
    const int l16 = lane & 15, lhi = lane >> 4;

    const int brow = blockIdx.y * GBM;
    const int bcol = blockIdx.x * GBN;
    const size_t cz = (size_t)blockIdx.z * NN;
    const unsigned char* Ab  = A  + cz + (size_t)brow * N2;
    const unsigned char* Btb = Bt + cz + (size_t)bcol * N2;

    // 8 stage chunks (16B) per thread per tile: L0..3 = A, L4..7 = B.
    // chunk g: row = g>>3, LDS slot = g&7, SRC slot = (g&7)^(row&7).
    const unsigned char* src[8];
    #pragma unroll
    for (int L = 0; L < 4; L++) {
        const int g = L * 256 + tid;
        const int r = g >> 3, s = (g & 7) ^ (r & 7);
        src[L] = Ab + (size_t)r * N2 + s * 16;
    }
    #pragma unroll
    for (int L = 4; L < 8; L++) {
        const int h = (L - 4) * 256 + tid;
        const int r = h >> 3, s = (h & 7) ^ (r & 7);
        src[L] = Btb + (size_t)r * N2 + s * 16;
    }

    #define STAGE8(buf, k0)                                                   \
        do {                                                                  \
            unsigned char* dst = lds + (buf) * BUF_BYTES + tid * 16;          \
            _Pragma("unroll")                                                 \
            for (int i = 0; i < 8; i++)                                       \
                gload16(src[i] + (k0), dst + i * 4096);                       \
        } while (0)

    f32x4 acc[4][4] = {};

    STAGE8(0, 0);
    STAGE8(1, GBK);

    const int nt = N2 / GBK;   // 16
    for (int t = 0; t < nt; ++t) {
        const unsigned char* base = lds + (t & 1) * BUF_BYTES;

        if (t < nt - 1) asm volatile("s_waitcnt vmcnt(8)" ::: "memory");
        else            asm volatile("s_waitcnt vmcnt(0)" ::: "memory");
        __builtin_amdgcn_s_barrier();          // tile t staged for ALL waves
        __builtin_amdgcn_sched_barrier(0);

        i32x8 af[4], bfr[4];
        #pragma unroll
        for (int m = 0; m < 4; m++) {
            const int row = wr + m * 16 + l16;
            const unsigned char* rp = base + row * 128;
            const i32x4 lo = *(const i32x4*)(rp + (((2 * lhi)     ^ (row & 7)) * 16));
            const i32x4 hi = *(const i32x4*)(rp + (((2 * lhi + 1) ^ (row & 7)) * 16));
            #pragma unroll
            for (int q = 0; q < 4; q++) { af[m][q] = lo[q]; af[m][4 + q] = hi[q]; }
        }
        #pragma unroll
        for (int n = 0; n < 4; n++) {
            const int row = wc + n * 16 + l16;
            const unsigned char* rp = base + B_OFF + row * 128;
            const i32x4 lo = *(const i32x4*)(rp + (((2 * lhi)     ^ (row & 7)) * 16));
            const i32x4 hi = *(const i32x4*)(rp + (((2 * lhi + 1) ^ (row & 7)) * 16));
            #pragma unroll
            for (int q = 0; q < 4; q++) { bfr[n][q] = lo[q]; bfr[n][4 + q] = hi[q]; }
        }

        __builtin_amdgcn_s_setprio(1);
        #pragma unroll
        for (int m = 0; m < 4; m++)
            #pragma unroll
            for (int n = 0; n < 4; n++)
                acc[m][n] = __builtin_amdgcn_mfma_scale_f32_16x16x128_f8f6f4(
                    af[m], bfr[n], acc[m][n], 0, 0, 0, SCALE1, 0, SCALE1);
        __builtin_amdgcn_s_setprio(0);

        // all reads of buf[t%2] retired before this join (they feed MFMAs
        // pinned above); only then may staging overwrite it.
        __builtin_amdgcn_sched_barrier(0);
        __builtin_amdgcn_s_barrier();
        __builtin_amdgcn_sched_barrier(0);
        if (t + 2 < nt) STAGE8(t & 1, (t + 2) * GBK);
    }
    #undef STAGE8

    if constexpr (MODE == 0) {
        unsigned char* Cb = (unsigned char*)Cout + cz + (size_t)brow * N2 + bcol;
        #pragma unroll
        for (int m = 0; m < 4; m++) {
            const int r0 = wr + m * 16 + lhi * 4;
            #pragma unroll
            for (int n = 0; n < 4; n++) {
                const int c0 = wc + n * 16 + l16;
                #pragma unroll
                for (int j = 0; j < 4; j++)
                    Cb[(size_t)(r0 + j) * N2 + c0] = f2f8(acc[m][n][j]);
            }
        }
        const size_t pb = (size_t)(blockIdx.x * 2 + wn) * 4096
                        + (size_t)blockIdx.z * 2048 + brow + wr;
        #pragma unroll
        for (int m = 0; m < 4; m++)
            #pragma unroll
            for (int j = 0; j < 4; j++) {
                float ps = acc[m][0][j] + acc[m][1][j] + acc[m][2][j] + acc[m][3][j];
                ps += __shfl_xor(ps, 1);
                ps += __shfl_xor(ps, 2);
                ps += __shfl_xor(ps, 4);
                ps += __shfl_xor(ps, 8);
                if (l16 == 0) P[pb + m * 16 + lhi * 4 + j] = ps;
            }
    } else {
        float* Cb = (float*)Cout + cz + (size_t)brow * N2 + bcol;
        float sf[4][4];
        #pragma unroll
        for (int m = 0; m < 4; m++)
            #pragma unroll
            for (int j = 0; j < 4; j++)
                sf[m][j] = sfac[blockIdx.z * 2048 + brow + wr + m * 16 + lhi * 4 + j];
        #pragma unroll
        for (int m = 0; m < 4; m++) {
            const int r0 = wr + m * 16 + lhi * 4;
            #pragma unroll
            for (int n = 0; n < 4; n++) {
                const int c0 = wc + n * 16 + l16;
                #pragma unroll
                for (int j = 0; j < 4; j++)
                    Cb[(size_t)(r0 + j) * N2 + c0] = acc[m][n][j] * sf[m][j];
            }
        }
    }
}

// ---------------------------------------------------------------------------
// merged gemv+dinv (unchanged)
// ---------------------------------------------------------------------------
__device__ __forceinline__ float block_sum256(float v) {
    #pragma unroll
    for (int off = 32; off; off >>= 1) v += __shfl_xor(v, off, 64);
    __shared__ float wsum[4];
    if ((threadIdx.x & 63) == 0) wsum[threadIdx.x >> 6] = v;
    __syncthreads();
    return wsum[0] + wsum[1] + wsum[2] + wsum[3];
}

__global__ __launch_bounds__(256) void gemv_sfac_kernel(
    const unsigned char* __restrict__ C0, const float* __restrict__ b2sum,
    const float* __restrict__ P, float* __restrict__ sfac) {
    const size_t r = blockIdx.x;               // 0..4095 (c*2048 + row)
    const int tid = threadIdx.x;

    float s0 = 0.f;
    if (tid < 64) {
        float v = P[(size_t)(tid & 31) * 4096 + r];
        v += __shfl_xor(v, 1);
        v += __shfl_xor(v, 2);
        v += __shfl_xor(v, 4);
        v += __shfl_xor(v, 8);
        v += __shfl_xor(v, 16);
        s0 = v;
    }

    const unsigned char* row = C0 + r * N2;
    const float* bs = b2sum + ((r >> 11) << 11);
    const int base = tid * 8;
    union { uint2 v; unsigned char b[8]; } u;
    u.v = *(const uint2*)&row[base];
    float sum = 0.f;
    #pragma unroll
    for (int i = 0; i < 8; i++) sum += f82f(u.b[i]) * bs[base + i];
    const float tot = block_sum256(sum);
    if (tid == 0) {
        const float d0 = s0 > 0.f ? rsqrtf(s0) : 0.f;
        const float deg1 = d0 * tot;
        sfac[r] = d0 * (deg1 > 0.f ? rsqrtf(deg1) : 0.f);
    }
}

// ---------------------------------------------------------------------------
// head: 64 blocks x 8 targets; block 0 also emits all_Ws. Unchanged.
// ---------------------------------------------------------------------------
__global__ __launch_bounds__(256) void head_kernel(
    const float* __restrict__ X, const float* __restrict__ gcn_w,
    const float* __restrict__ gcn_b, const float* __restrict__ lin_w,
    const float* __restrict__ lin_b, const int* __restrict__ tx,
    const float* __restrict__ w01, const float* __restrict__ w02,
    const float* __restrict__ w11,
    float* __restrict__ y, float* __restrict__ allw) {
    __shared__ float xr[8][512];    // 16 KB
    __shared__ float xk[8][132];    // padded
    __shared__ int trg[8];
    const int tid = threadIdx.x, b = blockIdx.x;
    if (tid < 8) trg[tid] = tx[b * 8 + tid];
    __syncthreads();
    #pragma unroll
    for (int q = 0; q < 4; q++) {
        const int idx = q * 1024 + tid * 4;
        const int t = idx >> 9, col = idx & 511;
        *(float4*)&xr[t][col] = *(const float4*)&X[(size_t)trg[t] * 512 + col];
    }
    __syncthreads();
    const int k = tid & 127, tp = tid >> 7;
    const float* wrp = gcn_w + (size_t)k * 512;
    float d[4] = {0.f, 0.f, 0.f, 0.f};
    for (int i = 0; i < 512; i += 4) {
        const float4 wv = *(const float4*)&wrp[i];
        #pragma unroll
        for (int tt = 0; tt < 4; tt++) {
            const float* xp = xr[tp * 4 + tt];
            d[tt] += xp[i] * wv.x + xp[i+1] * wv.y + xp[i+2] * wv.z + xp[i+3] * wv.w;
        }
    }
    const float gb = gcn_b[k];
    #pragma unroll
    for (int tt = 0; tt < 4; tt++) xk[tp * 4 + tt][k] = fmaxf(d[tt] + gb, 0.f);
    __syncthreads();
    if (tid < 64) {
        const int t = tid >> 3, o = tid & 7;
        float a = lin_b[o];
        const float* lw = lin_w + o * 256;
        for (int kk = 0; kk < 128; kk++)
            a += xk[t][kk] * (lw[kk] + lw[128 + kk]);
        y[(size_t)(b * 8 + t) * 8 + o] = a;
    }
    if (b == 0 && tid >= 64 && tid < 70) {
        const int t6 = tid - 64;
        const int wi = t6 >> 1, c = t6 & 1;
        const float* w = (wi == 0 ? w01 : (wi == 1 ? w02 : w11)) + c * 5;
        float mx = w[0];
        for (int e = 1; e < 5; e++) mx = fmaxf(mx, w[e]);
        float ex[5], sum = 0.f;
        for (int e = 0; e < 5; e++) { ex[e] = expf(w[e] - mx); sum += ex[e]; }
        for (int e = 0; e < 5; e++) allw[t6 * 5 + e] = ex[e] / sum;
    }
}

// ---------------------------------------------------------------------------
extern "C" void kernel_launch(void* const* d_in, const int* in_sizes, int n_in,
                              void* d_out, int out_size, void* d_ws, size_t ws_size,
                              hipStream_t stream) {
    const float* A     = (const float*)d_in[0];
    const float* X     = (const float*)d_in[1];
    const float* w01   = (const float*)d_in[2];
    const float* w02   = (const float*)d_in[3];
    const float* w11   = (const float*)d_in[4];
    const float* gcn_w = (const float*)d_in[5];
    const float* gcn_b = (const float*)d_in[6];
    const float* lin_w = (const float*)d_in[7];
    const float* lin_b = (const float*)d_in[8];
    const int*   tx    = (const int*)d_in[9];

    float* out  = (float*)d_out;
    float* y    = out;                 // [512, 8]
    float* allw = out + 4096;          // [3, 2, 5]
    float* H    = out + 4126;          // [2, 2048, 2048] fp32 final output

    unsigned char* HA   = (unsigned char*)d_ws;         // [2,N,N] fp8
    unsigned char* HBt  = HA + 2 * NN;                  // [2,N,N] fp8 (B^T)
    unsigned char* HB2t = HBt + 2 * NN;                 // [2,N,N] fp8 (B^T)
    unsigned char* C0   = HB2t + 2 * NN;                // [2,N,N] fp8 layer-0 product
    float* P     = (float*)(C0 + 2 * NN);               // [32][4096] partials (f32)
    float* PB2   = P + 32 * 4096;                       // [2][32][2048]
    float* b2sum = PB2 + 2 * 32 * 2048;                 // [4096]
    float* sfac  = b2sum + 4096;                        // [4096]

    combine_kernel<<<dim3(32, 64), 512, 0, stream>>>(A, w01, w02, w11,
                                                     HA, HBt, HB2t, PB2);
    b2fold_kernel<<<16, 256, 0, stream>>>(PB2, b2sum);
    gemm_mx<0><<<dim3(16, 16, 2), 256, 0, stream>>>(HA, HBt, C0, P, nullptr);
    gemv_sfac_kernel<<<4096, 256, 0, stream>>>(C0, b2sum, P, sfac);
    gemm_mx<1><<<dim3(16, 16, 2), 256, 0, stream>>>(C0, HB2t, H, nullptr, sfac);
    head_kernel<<<64, 256, 0, stream>>>(X, gcn_w, gcn_b, lin_w, lin_b, tx,
                                        w01, w02, w11, y, allw);
}